// Round 3
// baseline (21329.742 us; speedup 1.0000x reference)
//
#include <hip/hip_runtime.h>
#include <hip/hip_bf16.h>

#define NWG 256   // persistent workgroups == #CUs; each owns 4 hidden units
#define NTH 512   // 8 waves; wave w owns gate-rows 2w,2w+1 of the WG's 16
#define T1  8192  // S*W word steps
#define SS  64
#define WW  128

typedef unsigned long long u64;

// ws layout (8B units): [0..2047] hbuf64 (2 slots x 1024 tagged h),
// [2048..67583] encs64 (64 x 1024 tagged), [67584..67839] part64 (256 tagged)
// memset to 0 each call (tag 0 == invalid; valid tags start at 1)

__device__ __forceinline__ u64 aload(const u64* p) {
  return __hip_atomic_load(p, __ATOMIC_RELAXED, __HIP_MEMORY_SCOPE_AGENT);
}
__device__ __forceinline__ void astore(u64* p, u64 v) {
  __hip_atomic_store(p, v, __ATOMIC_RELAXED, __HIP_MEMORY_SCOPE_AGENT);
}
__device__ __forceinline__ u64 pack(float v, unsigned tag) {
  return ((u64)tag << 32) | (u64)__float_as_uint(v);
}

// spin until both owned columns (tid, tid+512) carry TAG, then deposit to DST
#define SPIN_STAGE2(SRCP, TAG, DST) do {                                  \
    const u64* _p = (SRCP); const unsigned _t = (TAG); u64 _a, _b;        \
    for (;;) {                                                            \
      _a = aload(_p + tid); _b = aload(_p + 512 + tid);                   \
      if ((((unsigned)(_a >> 32)) == _t) && (((unsigned)(_b >> 32)) == _t)) break; \
    }                                                                     \
    (DST)[tid]       = __uint_as_float((unsigned)_a);                     \
    (DST)[512 + tid] = __uint_as_float((unsigned)_b);                     \
  } while (0)

__global__ __launch_bounds__(NTH, 1)
void lstm_hier_attn(const float* __restrict__ xin,
                    const float* __restrict__ h1_0, const float* __restrict__ c1_0,
                    const float* __restrict__ h2_0, const float* __restrict__ c2_0,
                    const float* __restrict__ Wih1, const float* __restrict__ Whh1,
                    const float* __restrict__ bih1, const float* __restrict__ bhh1,
                    const float* __restrict__ Wih2, const float* __restrict__ Whh2,
                    const float* __restrict__ bih2, const float* __restrict__ bhh2,
                    const float* __restrict__ attw, const float* __restrict__ atts,
                    const float* __restrict__ Wf,   const float* __restrict__ bfb,
                    u64* hbuf64, u64* encs64, u64* part64, float* out)
{
  const int wid = blockIdx.x;
  const int tid = threadIdx.x;
  const int wv  = tid >> 6;   // wave id 0..7
  const int l   = tid & 63;   // lane
  const int u0  = wid << 2;   // first hidden unit owned by this WG

  __shared__ float h_lds[1024];
  __shared__ float e_lds[1024];
  __shared__ float aw_lds[WW];
  __shared__ float as_lds[SS];
  __shared__ float g_lds[16];
  __shared__ float c_lds[4];
  __shared__ float enc_lds[4];
  __shared__ float row_lds[4];

  if (tid == 0) {   // one-time softmaxes (overlaps other WGs' weight loads)
    float m = -1e30f;
    for (int i = 0; i < WW; ++i) m = fmaxf(m, attw[i]);
    float ssum = 0.f;
    for (int i = 0; i < WW; ++i) { float e = __expf(attw[i] - m); aw_lds[i] = e; ssum += e; }
    float inv = 1.f / ssum;
    for (int i = 0; i < WW; ++i) aw_lds[i] *= inv;
    m = -1e30f;
    for (int i = 0; i < SS; ++i) m = fmaxf(m, atts[i]);
    ssum = 0.f;
    for (int i = 0; i < SS; ++i) { float e = __expf(atts[i] - m); as_lds[i] = e; ssum += e; }
    inv = 1.f / ssum;
    for (int i = 0; i < SS; ++i) as_lds[i] *= inv;
  }
  if (tid < 4) {
    c_lds[tid]   = c1_0[u0 + tid];
    enc_lds[tid] = 0.f;
    row_lds[tid] = 0.f;
  }

  // layer-1 weights: thread (wv,l) holds gate-rows r=2wv,2wv+1 (r = gate*4+j),
  // columns jj*64+l. 64 floats/thread — fits regalloc naturally.
  float wih[2][16], whh[2][16], bias[2];
#pragma unroll
  for (int t = 0; t < 2; ++t) {
    const int r    = (wv << 1) + t;
    const int grow = ((r >> 2) << 10) + u0 + (r & 3);
    bias[t] = bih1[grow] + bhh1[grow];
    const float* pih = Wih1 + (size_t)grow * 1024 + l;
    const float* phh = Whh1 + (size_t)grow * 1024 + l;
#pragma unroll
    for (int jj = 0; jj < 16; ++jj) {
      wih[t][jj] = pih[jj * 64];
      whh[t][jj] = phh[jj * 64];
    }
  }
#pragma unroll
  for (int t = 0; t < 2; ++t)
#pragma unroll
    for (int jj = 0; jj < 16; ++jj) {
      asm volatile("" : "+v"(wih[t][jj]));
      asm volatile("" : "+v"(whh[t][jj]));
    }
  __syncthreads();

  // ======================= layer 1: 8192 word steps =======================
  for (int s = 0; s < T1; ++s) {
    // issue x-row loads early; consumed after the spin
    const float* xrow = xin + (size_t)s * 1024 + l;
    float xv[16];
#pragma unroll
    for (int jj = 0; jj < 16; ++jj) xv[jj] = xrow[jj * 64];

    if (s > 0) {
      SPIN_STAGE2(hbuf64 + ((size_t)(s & 1) << 10), (unsigned)s, h_lds);
    } else {
      h_lds[tid]       = h1_0[tid];
      h_lds[512 + tid] = h1_0[512 + tid];
    }
    __syncthreads();   // B1: h_lds ready

    float a0 = 0.f, a1 = 0.f;
#pragma unroll
    for (int jj = 0; jj < 16; ++jj) {
      const float xvj = xv[jj];
      a0 += wih[0][jj] * xvj; a1 += wih[1][jj] * xvj;
      const float hv = h_lds[(jj << 6) + l];
      a0 += whh[0][jj] * hv;  a1 += whh[1][jj] * hv;
    }
#pragma unroll
    for (int m = 1; m < 64; m <<= 1) {
      a0 += __shfl_xor(a0, m); a1 += __shfl_xor(a1, m);
    }
    if (l == 0) {
      g_lds[(wv << 1) + 0] = a0 + bias[0];
      g_lds[(wv << 1) + 1] = a1 + bias[1];
    }
    __syncthreads();   // B2: g_lds ready; all h_lds/e_lds reads of step s done
    if (tid < 4) {                       // torch gate order: i,f,g,o
      const int j = tid;
      const float ig = g_lds[0 + j], fg = g_lds[4 + j], gg = g_lds[8 + j], og = g_lds[12 + j];
      const float si = 1.f / (1.f + __expf(-ig));
      const float sf = 1.f / (1.f + __expf(-fg));
      const float so = 1.f / (1.f + __expf(-og));
      const float c  = sf * c_lds[j] + si * tanhf(gg);
      const float h  = so * tanhf(c);
      c_lds[j] = c;
      const int wd = s & (WW - 1);
      float e = enc_lds[j] + aw_lds[wd] * h;          // enc = aw @ hs (online)
      u64* dst = hbuf64 + ((size_t)((s + 1) & 1) << 10);
      astore(&dst[u0 + j], pack(h, (unsigned)(s + 1)));
      if (wd == WW - 1) {
        astore(&encs64[((size_t)(s >> 7) << 10) + u0 + j], pack(e, (unsigned)((s >> 7) + 1)));
        e = 0.f;
      }
      enc_lds[j] = e;
    }
    // no trailing barrier: any thread's next-step spin succeeds only after ALL
    // WGs (incl. ours, via wave 0 after B2) store tag s+1 — so deposits for
    // s+1 cannot precede completion of step-s LDS reads.
  }

  // ======================= layer 2: 64 sentence steps =======================
#pragma unroll
  for (int t = 0; t < 2; ++t) {          // reuse the same VGPRs for layer-2 weights
    const int r    = (wv << 1) + t;
    const int grow = ((r >> 2) << 10) + u0 + (r & 3);
    bias[t] = bih2[grow] + bhh2[grow];
    const float* pih = Wih2 + (size_t)grow * 1024 + l;
    const float* phh = Whh2 + (size_t)grow * 1024 + l;
#pragma unroll
    for (int jj = 0; jj < 16; ++jj) {
      wih[t][jj] = pih[jj * 64];
      whh[t][jj] = phh[jj * 64];
    }
  }
#pragma unroll
  for (int t = 0; t < 2; ++t)
#pragma unroll
    for (int jj = 0; jj < 16; ++jj) {
      asm volatile("" : "+v"(wih[t][jj]));
      asm volatile("" : "+v"(whh[t][jj]));
    }
  if (tid < 4) c_lds[tid] = c2_0[u0 + tid];

  for (int s2 = 0; s2 < SS; ++s2) {
    const unsigned hs = (unsigned)(T1 + s2);
    // h spin first — it is the ordering gate. s2==0 spins for tag 8192 (slot 0)
    // to close the layer-boundary overwrite hazard, then overrides with h2_0.
    SPIN_STAGE2(hbuf64 + ((size_t)(hs & 1) << 10), hs, h_lds);
    SPIN_STAGE2(encs64 + ((size_t)s2 << 10), (unsigned)(s2 + 1), e_lds);
    if (s2 == 0) {
      h_lds[tid]       = h2_0[tid];
      h_lds[512 + tid] = h2_0[512 + tid];
    }
    __syncthreads();   // B1

    float a0 = 0.f, a1 = 0.f;
#pragma unroll
    for (int jj = 0; jj < 16; ++jj) {
      const float ev = e_lds[(jj << 6) + l];
      a0 += wih[0][jj] * ev; a1 += wih[1][jj] * ev;
      const float hv = h_lds[(jj << 6) + l];
      a0 += whh[0][jj] * hv; a1 += whh[1][jj] * hv;
    }
#pragma unroll
    for (int m = 1; m < 64; m <<= 1) {
      a0 += __shfl_xor(a0, m); a1 += __shfl_xor(a1, m);
    }
    if (l == 0) {
      g_lds[(wv << 1) + 0] = a0 + bias[0];
      g_lds[(wv << 1) + 1] = a1 + bias[1];
    }
    __syncthreads();   // B2
    if (tid < 4) {
      const int j = tid;
      const float ig = g_lds[0 + j], fg = g_lds[4 + j], gg = g_lds[8 + j], og = g_lds[12 + j];
      const float si = 1.f / (1.f + __expf(-ig));
      const float sf = 1.f / (1.f + __expf(-fg));
      const float so = 1.f / (1.f + __expf(-og));
      const float c  = sf * c_lds[j] + si * tanhf(gg);
      const float h  = so * tanhf(c);
      c_lds[j] = c;
      row_lds[j] += as_lds[s2] * h;                    // row = asn @ hs2 (online)
      u64* dst = hbuf64 + ((size_t)((hs + 1) & 1) << 10);
      astore(&dst[u0 + j], pack(h, hs + 1));
    }
    // deposits for s2+1 gated by the h spin (needs our wave-0 store, post-B2)
  }

  // =================== final projection + sigmoid ===================
  if (tid == 0) {
    const float p = row_lds[0] * Wf[u0 + 0] + row_lds[1] * Wf[u0 + 1]
                  + row_lds[2] * Wf[u0 + 2] + row_lds[3] * Wf[u0 + 3];
    astore(&part64[wid], pack(p, 1u));
  }
  if (wid == 0) {
    if (tid < 256) {
      u64 a;
      for (;;) { a = aload(&part64[tid]); if ((unsigned)(a >> 32) == 1u) break; }
      h_lds[tid] = __uint_as_float((unsigned)a);
    }
    __syncthreads();
    if (wv == 0) {
      float p = h_lds[l] + h_lds[64 + l] + h_lds[128 + l] + h_lds[192 + l];
#pragma unroll
      for (int m = 1; m < 64; m <<= 1) p += __shfl_xor(p, m);
      if (l == 0) out[0] = 1.f / (1.f + __expf(-(p + bfb[0])));
    }
  }
}

extern "C" void kernel_launch(void* const* d_in, const int* in_sizes, int n_in,
                              void* d_out, int out_size, void* d_ws, size_t ws_size,
                              hipStream_t stream) {
  (void)in_sizes; (void)n_in; (void)out_size; (void)ws_size;
  const float* xin  = (const float*)d_in[0];
  const float* h1   = (const float*)d_in[1];
  const float* c1   = (const float*)d_in[2];
  const float* h2   = (const float*)d_in[3];
  const float* c2   = (const float*)d_in[4];
  const float* Wih1 = (const float*)d_in[5];
  const float* Whh1 = (const float*)d_in[6];
  const float* bih1 = (const float*)d_in[7];
  const float* bhh1 = (const float*)d_in[8];
  const float* Wih2 = (const float*)d_in[9];
  const float* Whh2 = (const float*)d_in[10];
  const float* bih2 = (const float*)d_in[11];
  const float* bhh2 = (const float*)d_in[12];
  const float* attw = (const float*)d_in[13];
  const float* atts = (const float*)d_in[14];
  const float* Wf   = (const float*)d_in[15];
  const float* bfb  = (const float*)d_in[16];

  u64* hbuf64 = (u64*)d_ws;                 // 2048 u64
  u64* encs64 = hbuf64 + 2048;              // 65536 u64
  u64* part64 = encs64 + 65536;             // 256 u64
  float* out  = (float*)d_out;

  // tags must start invalid (0) every call — replay-safe, graph-capture legal
  hipMemsetAsync(d_ws, 0, (2048 + 65536 + 256) * sizeof(u64), stream);
  lstm_hier_attn<<<dim3(NWG), dim3(NTH), 0, stream>>>(
      xin, h1, c1, h2, c2, Wih1, Whh1, bih1, bhh1,
      Wih2, Whh2, bih2, bhh2, attw, atts, Wf, bfb,
      hbuf64, encs64, part64, out);
}